// Round 1
// baseline (201.506 us; speedup 1.0000x reference)
//
#include <hip/hip_runtime.h>
#include <math.h>

#define EPS 1e-6f

// One block per (n,h). D = M = 64 hard-wired (matches reference shapes).
__global__ __launch_bounds__(256) void rla_kernel(
    const float* __restrict__ query,   // (NH, 64)
    const float* __restrict__ key,     // (NH, 64)
    const float* __restrict__ value,   // (NH, 64)
    const float* __restrict__ Si,      // (NH, 64, 64)
    const float* __restrict__ Zi,      // (NH, 64)
    float* __restrict__ Vout,          // (NH, 64)
    float* __restrict__ Si_out,        // (NH, 64, 64)
    float* __restrict__ Zi_out)        // (NH, 64)
{
    const int nh   = blockIdx.x;
    const int t    = threadIdx.x;      // 0..255
    const int col4 = t & 15;           // float4 column in m (m = 4*col4..4*col4+3)
    const int drow = t >> 4;           // 0..15

    __shared__ float Qs[64], Ks[64], Vs[64], Zin[64];
    __shared__ float Zsh;
    __shared__ float4 red[256];

    const size_t base64 = (size_t)nh * 64;

    // Stage small per-(n,h) vectors; compute feature maps and Zi_new.
    if (t < 64) {
        float q = query[base64 + t];
        float k = key[base64 + t];
        float Qv = q > 0.f ? q + 1.f : expf(q);     // elu(x)+1
        float Kv = k > 0.f ? k + 1.f : expf(k);
        Qs[t] = Qv;
        Ks[t] = Kv;
        Vs[t] = value[base64 + t];
        float zn = Zi[base64 + t] + Kv;
        Zin[t] = zn;
        Zi_out[base64 + t] = zn;                    // output 2
    }
    __syncthreads();

    // Z = 1 / (dot(Q, Zi_new) + eps) — wave-64 butterfly in wave 0.
    if (t < 64) {
        float p = Qs[t] * Zin[t];
        #pragma unroll
        for (int off = 32; off >= 1; off >>= 1)
            p += __shfl_down(p, off);
        if (t == 0) Zsh = 1.f / (p + EPS);
    }
    __syncthreads();

    const float4* Si4 = (const float4*)(Si     + (size_t)nh * 4096);
    float4*       So4 = (float4*)      (Si_out + (size_t)nh * 4096);
    const float4  v4  = ((const float4*)Vs)[col4];

    // Stream the 64x64 Si tile: fuse Si_new write-back with V accumulation.
    float4 acc = make_float4(0.f, 0.f, 0.f, 0.f);
    #pragma unroll
    for (int kk = 0; kk < 4; ++kk) {
        const int f = t + 256 * kk;    // float4 index within the tile
        const int d = f >> 4;          // row; col4 = f & 15 == t & 15 (invariant)
        const float Kd = Ks[d];
        const float Qd = Qs[d];
        float4 si = Si4[f];
        float4 sn;
        sn.x = si.x + Kd * v4.x;
        sn.y = si.y + Kd * v4.y;
        sn.z = si.z + Kd * v4.z;
        sn.w = si.w + Kd * v4.w;
        So4[f] = sn;                   // output 1 (Si_new)
        acc.x += Qd * sn.x;
        acc.y += Qd * sn.y;
        acc.z += Qd * sn.z;
        acc.w += Qd * sn.w;
    }

    // Reduce acc over the 16 d-groups (threads sharing col4, stride 16).
    red[t] = acc;
    __syncthreads();
    #pragma unroll
    for (int s = 8; s >= 1; s >>= 1) {
        if (drow < s) {
            float4 o = red[t + 16 * s];
            float4 m = red[t];
            m.x += o.x; m.y += o.y; m.z += o.z; m.w += o.w;
            red[t] = m;
        }
        __syncthreads();
    }
    if (drow == 0) {
        const float z = Zsh;
        float4 r = red[t];
        float4 outv;
        outv.x = r.x * z; outv.y = r.y * z; outv.z = r.z * z; outv.w = r.w * z;
        ((float4*)(Vout + base64))[col4] = outv;   // output 0 (V)
    }
}

extern "C" void kernel_launch(void* const* d_in, const int* in_sizes, int n_in,
                              void* d_out, int out_size, void* d_ws, size_t ws_size,
                              hipStream_t stream) {
    const float* query = (const float*)d_in[0];
    const float* key   = (const float*)d_in[1];
    const float* value = (const float*)d_in[2];
    const float* Si    = (const float*)d_in[3];
    const float* Zi    = (const float*)d_in[4];

    const int NH = in_sizes[0] / 64;            // N*H (D = 64)
    float* out    = (float*)d_out;
    float* Vout   = out;                        // (NH, 64)
    float* Si_out = out + (size_t)NH * 64;      // (NH, 64, 64)
    float* Zi_out = Si_out + (size_t)NH * 4096; // (NH, 64)

    rla_kernel<<<NH, 256, 0, stream>>>(query, key, value, Si, Zi,
                                       Vout, Si_out, Zi_out);
}

// Round 3
// 186.091 us; speedup vs baseline: 1.0828x; 1.0828x over previous
//
#include <hip/hip_runtime.h>
#include <math.h>

#define EPS 1e-6f

typedef float floatx4 __attribute__((ext_vector_type(4)));

// One WAVE (64 lanes) per (n,h). D = M = 64 hard-wired.
// No LDS, no __syncthreads — all cross-lane via shuffles; waves independent.
__global__ __launch_bounds__(256) void rla_kernel(
    const float* __restrict__ query,   // (NH, 64)
    const float* __restrict__ key,     // (NH, 64)
    const float* __restrict__ value,   // (NH, 64)
    const float* __restrict__ Si,      // (NH, 64, 64)
    const float* __restrict__ Zi,      // (NH, 64)
    float* __restrict__ Vout,          // (NH, 64)
    float* __restrict__ Si_out,        // (NH, 64, 64)
    float* __restrict__ Zi_out)        // (NH, 64)
{
    const int wid  = threadIdx.x >> 6;          // wave 0..3 within block
    const int lane = threadIdx.x & 63;
    const int nh   = blockIdx.x * 4 + wid;

    const size_t base64 = (size_t)nh * 64;

    // Per-lane staging of the small vectors (fully coalesced, 256 B/wave each).
    float q  = query[base64 + lane];
    float k  = key[base64 + lane];
    float Qv = q > 0.f ? q + 1.f : __expf(q);   // elu(x)+1
    float Kv = k > 0.f ? k + 1.f : __expf(k);
    float vv = value[base64 + lane];
    float zn = Zi[base64 + lane] + Kv;
    Zi_out[base64 + lane] = zn;                 // output 2 (Zi_new)

    // Z = 1 / (dot(Q, Zi_new) + eps) — wave-64 butterfly, result in all lanes.
    float p = Qv * zn;
    #pragma unroll
    for (int off = 32; off >= 1; off >>= 1)
        p += __shfl_xor(p, off);
    const float Zinv = 1.f / (p + EPS);

    const int col4 = lane & 15;                 // float4 column in m
    const int dgrp = lane >> 4;                 // 0..3

    // v4 = value[4*col4 .. 4*col4+3], gathered from lanes 4*col4+j.
    floatx4 v4;
    v4.x = __shfl(vv, 4 * col4 + 0);
    v4.y = __shfl(vv, 4 * col4 + 1);
    v4.z = __shfl(vv, 4 * col4 + 2);
    v4.w = __shfl(vv, 4 * col4 + 3);

    const floatx4* Si4 = (const floatx4*)(Si     + (size_t)nh * 4096);
    floatx4*       So4 = (floatx4*)      (Si_out + (size_t)nh * 4096);

    // Stream the 64x64 Si tile: 16 iters x (1 KiB load + 1 KiB store) per wave.
    // Row d = dgrp + 4*kk; Q[d], K[d] broadcast from lane d.
    floatx4 acc = (floatx4)0.f;
    #pragma unroll
    for (int kk = 0; kk < 16; ++kk) {
        const int f = lane + (kk << 6);         // contiguous 1 KiB per wave
        const int d = dgrp + (kk << 2);
        const float Kd = __shfl(Kv, d);
        const float Qd = __shfl(Qv, d);
        floatx4 si = __builtin_nontemporal_load(&Si4[f]);
        floatx4 sn = si + Kd * v4;
        __builtin_nontemporal_store(sn, &So4[f]);   // output 1 (Si_new)
        acc += Qd * sn;
    }

    // Reduce acc over the 4 d-groups (lanes l, l^16, l^32, l^48).
    #pragma unroll
    for (int off = 32; off >= 16; off >>= 1) {
        acc.x += __shfl_xor(acc.x, off);
        acc.y += __shfl_xor(acc.y, off);
        acc.z += __shfl_xor(acc.z, off);
        acc.w += __shfl_xor(acc.w, off);
    }
    if (lane < 16) {
        floatx4 outv = acc * Zinv;
        ((floatx4*)(Vout + base64))[lane] = outv;   // output 0 (V)
    }
}

extern "C" void kernel_launch(void* const* d_in, const int* in_sizes, int n_in,
                              void* d_out, int out_size, void* d_ws, size_t ws_size,
                              hipStream_t stream) {
    const float* query = (const float*)d_in[0];
    const float* key   = (const float*)d_in[1];
    const float* value = (const float*)d_in[2];
    const float* Si    = (const float*)d_in[3];
    const float* Zi    = (const float*)d_in[4];

    const int NH = in_sizes[0] / 64;            // N*H (D = 64); 32768 here
    float* out    = (float*)d_out;
    float* Vout   = out;                        // (NH, 64)
    float* Si_out = out + (size_t)NH * 64;      // (NH, 64, 64)
    float* Zi_out = Si_out + (size_t)NH * 4096; // (NH, 64)

    rla_kernel<<<NH / 4, 256, 0, stream>>>(query, key, value, Si, Zi,
                                           Vout, Si_out, Zi_out);
}